// Round 2
// baseline (882.189 us; speedup 1.0000x reference)
//
#include <hip/hip_runtime.h>
#include <stdint.h>

#define NB 32          // batch size B (fixed by problem)
#define BIN_SHIFT 7    // 128 dst rows per bin
#define BIN_ROWS 128
#define NBINS_MAX 1024 // supports M <= 131072
#define FCHUNK 8192    // edges per hist/fill block (256 thr x 32)

// ---------------------------------------------------------------------------
// x (B, N) -> xt (N, B): 32x32 LDS tile transpose, coalesced read and write.
// ---------------------------------------------------------------------------
__global__ void transpose_x_kernel(const float* __restrict__ x,
                                   float* __restrict__ xt, int N) {
    __shared__ float tile[32][33];  // +1 pad: avoid bank conflicts
    int n0 = blockIdx.x * 32;
    for (int i = threadIdx.y; i < 32; i += 8) {
        int n = n0 + threadIdx.x;
        tile[i][threadIdx.x] = (n < N) ? x[(size_t)i * N + n] : 0.f;
    }
    __syncthreads();
    for (int i = threadIdx.y; i < 32; i += 8) {
        int n = n0 + i;
        if (n < N) xt[(size_t)n * NB + threadIdx.x] = tile[threadIdx.x][i];
    }
}

// ---------------------------------------------------------------------------
// Per-bin histogram via per-block LDS histogram (one global atomic per
// nonzero (block,bin), not per edge).
// ---------------------------------------------------------------------------
__global__ void bin_hist(const int* __restrict__ dst,
                         int* __restrict__ binCnt, int nnz, int nbins) {
    __shared__ int lhist[NBINS_MAX];
    int t = threadIdx.x;
    for (int i = t; i < nbins; i += 256) lhist[i] = 0;
    __syncthreads();
    int e0 = blockIdx.x * FCHUNK;
#pragma unroll 4
    for (int k = 0; k < 32; ++k) {
        int e = e0 + k * 256 + t;
        if (e < nnz) atomicAdd(&lhist[dst[e] >> BIN_SHIFT], 1);
    }
    __syncthreads();
    for (int i = t; i < nbins; i += 256)
        if (lhist[i]) atomicAdd(&binCnt[i], lhist[i]);
}

// ---------------------------------------------------------------------------
// Exclusive scan of bin counts (single block; nbins <= 1024).
// binBase[nbins] = total. binCursor starts == binBase (fill claim pointers).
// ---------------------------------------------------------------------------
__global__ void bin_scan(const int* __restrict__ binCnt,
                         int* __restrict__ binBase,
                         int* __restrict__ binCursor, int nbins) {
    __shared__ int s[1024];
    int t = threadIdx.x;
    int v = (t < nbins) ? binCnt[t] : 0;
    s[t] = v;
    __syncthreads();
    for (int off = 1; off < 1024; off <<= 1) {
        int add = (t >= off) ? s[t - off] : 0;
        __syncthreads();
        s[t] += add;
        __syncthreads();
    }
    if (t < nbins) {
        int ex = s[t] - v;
        binBase[t]   = ex;
        binCursor[t] = ex;
    }
    if (t == 0) binBase[nbins] = s[1023];
}

// ---------------------------------------------------------------------------
// Binned fill: per-block LDS hist -> one cursor claim per (block,bin) ->
// ranked write. Same-bin edges from one block are CONTIGUOUS in csr, so
// scattered-line traffic is ~runs (84B avg) not ~edges (64B line each).
// Entry: meta = (dst&127)<<24 | src  (src < 2^24), val bits.
// ---------------------------------------------------------------------------
__global__ void bin_fill(const int* __restrict__ src,
                         const int* __restrict__ dst,
                         const float* __restrict__ vals,
                         int* __restrict__ binCursor,
                         uint2* __restrict__ csr, int nnz, int nbins) {
    __shared__ int lhist[NBINS_MAX];
    __shared__ int lbase[NBINS_MAX];
    int t = threadIdx.x;
    int e0 = blockIdx.x * FCHUNK;
    for (int i = t; i < nbins; i += 256) lhist[i] = 0;
    __syncthreads();
#pragma unroll 4
    for (int k = 0; k < 32; ++k) {
        int e = e0 + k * 256 + t;
        if (e < nnz) atomicAdd(&lhist[dst[e] >> BIN_SHIFT], 1);
    }
    __syncthreads();
    for (int i = t; i < nbins; i += 256) {
        int c = lhist[i];
        lbase[i] = c ? atomicAdd(&binCursor[i], c) : 0;
        lhist[i] = 0;  // reuse as intra-block rank cursor
    }
    __syncthreads();
#pragma unroll 4
    for (int k = 0; k < 32; ++k) {
        int e = e0 + k * 256 + t;
        if (e < nnz) {
            int d = dst[e];            // L2-hot: just read in pass 1
            int bin = d >> BIN_SHIFT;
            int r = atomicAdd(&lhist[bin], 1);
            uint32_t meta = ((uint32_t)(d & (BIN_ROWS - 1)) << 24) |
                            (uint32_t)src[e];
            csr[lbase[bin] + r] = make_uint2(meta, __float_as_uint(vals[e]));
        }
    }
}

// ---------------------------------------------------------------------------
// One block per bin: accumulate the bin's 128x32 output tile in LDS.
//  - csr stream: contiguous, uniform-per-halfwave 8B loads (L1-hot)
//  - xt gather: 32 lanes cover the 128B line (coalesced, L2/L3-resident)
//  - LDS atomicAdd: bank = lane -> 2 lanes/bank = free
//  - flush: one coalesced 16KB store, no global atomics, no yt memset
// ---------------------------------------------------------------------------
__global__ void bin_scatter(const int* __restrict__ binBase,
                            const uint2* __restrict__ csr,
                            const float* __restrict__ xt,
                            float* __restrict__ yt, int M) {
    __shared__ float tile[BIN_ROWS * NB];  // 16 KB
    int t = threadIdx.x;
    int bin = blockIdx.x;
    // zero tile
    for (int i = t * 4; i < BIN_ROWS * NB; i += 256 * 4)
        *(float4*)&tile[i] = make_float4(0.f, 0.f, 0.f, 0.f);
    __syncthreads();

    int start = binBase[bin];
    int end   = binBase[bin + 1];
    int g = t >> 5;       // half-wave id 0..7
    int b = t & 31;       // batch lane
    int j = start + g;
    // 4-deep unroll: 4 independent xt lines in flight per half-wave
    for (; j + 24 < end; j += 32) {
        uint2 e0 = csr[j];
        uint2 e1 = csr[j + 8];
        uint2 e2 = csr[j + 16];
        uint2 e3 = csr[j + 24];
        float x0 = xt[(size_t)(e0.x & 0xFFFFFF) * NB + b];
        float x1 = xt[(size_t)(e1.x & 0xFFFFFF) * NB + b];
        float x2 = xt[(size_t)(e2.x & 0xFFFFFF) * NB + b];
        float x3 = xt[(size_t)(e3.x & 0xFFFFFF) * NB + b];
        atomicAdd(&tile[(e0.x >> 24) * NB + b], __uint_as_float(e0.y) * x0);
        atomicAdd(&tile[(e1.x >> 24) * NB + b], __uint_as_float(e1.y) * x1);
        atomicAdd(&tile[(e2.x >> 24) * NB + b], __uint_as_float(e2.y) * x2);
        atomicAdd(&tile[(e3.x >> 24) * NB + b], __uint_as_float(e3.y) * x3);
    }
    for (; j < end; j += 8) {
        uint2 e = csr[j];
        float xv = xt[(size_t)(e.x & 0xFFFFFF) * NB + b];
        atomicAdd(&tile[(e.x >> 24) * NB + b], __uint_as_float(e.y) * xv);
    }
    __syncthreads();

    size_t row0 = (size_t)bin * BIN_ROWS;
    int rows = min(BIN_ROWS, (int)(M - row0));
    float* dstp = yt + row0 * NB;
    if (rows == BIN_ROWS) {
        for (int i = t * 4; i < BIN_ROWS * NB; i += 256 * 4)
            *(float4*)&dstp[i] = *(float4*)&tile[i];
    } else {
        int lim = rows * NB;
        for (int i = t; i < lim; i += 256) dstp[i] = tile[i];
    }
}

// ---------------------------------------------------------------------------
// yt (M, B) -> out (B, M), + bias: 32x32 LDS tile transpose.
// ---------------------------------------------------------------------------
__global__ void finalize_kernel(const float* __restrict__ yt,
                                const float* __restrict__ bias,
                                float* __restrict__ out, int M) {
    __shared__ float tile[32][33];
    int m0 = blockIdx.x * 32;
    for (int i = threadIdx.y; i < 32; i += 8) {
        int m = m0 + i;
        tile[i][threadIdx.x] = (m < M) ? yt[(size_t)m * NB + threadIdx.x] : 0.f;
    }
    __syncthreads();
    for (int i = threadIdx.y; i < 32; i += 8) {
        int m = m0 + threadIdx.x;
        if (m < M) out[(size_t)i * M + m] = tile[threadIdx.x][i] + bias[m];
    }
}

extern "C" void kernel_launch(void* const* d_in, const int* in_sizes, int n_in,
                              void* d_out, int out_size, void* d_ws, size_t ws_size,
                              hipStream_t stream) {
    const float* x       = (const float*)d_in[0];   // (B, N, 1) fp32
    const int*   indices = (const int*)  d_in[1];   // (2, NNZ) int32
    const float* vals    = (const float*)d_in[2];   // (NNZ,) fp32
    const float* bias    = (const float*)d_in[3];   // (M, 1) fp32

    float* out = (float*)d_out;                     // (B, M, 1) fp32

    int nnz = in_sizes[1] / 2;
    int N   = in_sizes[0] / NB;
    int M   = in_sizes[3];

    const int* src = indices;        // row 0
    const int* dst = indices + nnz;  // row 1

    int nbins = (M + BIN_ROWS - 1) >> BIN_SHIFT;   // 782 for M=100000

    // workspace layout:
    //   xt        N*NB f32   (12.8 MB)
    //   yt        M*NB f32   (12.8 MB)
    //   binCnt    NBINS_MAX i32
    //   binBase   NBINS_MAX+1 i32
    //   binCursor NBINS_MAX i32
    //   csr       NNZ uint2  (25.6 MB)
    float* xt        = (float*)d_ws;
    float* yt        = xt + (size_t)N * NB;
    int*   binCnt    = (int*)(yt + (size_t)M * NB);
    int*   binBase   = binCnt + NBINS_MAX;
    int*   binCursor = binBase + NBINS_MAX + 1;
    uint2* csr       = (uint2*)(((uintptr_t)(binCursor + NBINS_MAX) + 15) &
                                ~(uintptr_t)15);

    transpose_x_kernel<<<(N + 31) / 32, dim3(32, 8), 0, stream>>>(x, xt, N);

    hipMemsetAsync(binCnt, 0, nbins * sizeof(int), stream);

    int fgrid = (nnz + FCHUNK - 1) / FCHUNK;  // 391
    bin_hist<<<fgrid, 256, 0, stream>>>(dst, binCnt, nnz, nbins);
    bin_scan<<<1, 1024, 0, stream>>>(binCnt, binBase, binCursor, nbins);
    bin_fill<<<fgrid, 256, 0, stream>>>(src, dst, vals, binCursor, csr, nnz, nbins);

    bin_scatter<<<nbins, 256, 0, stream>>>(binBase, csr, xt, yt, M);

    finalize_kernel<<<(M + 31) / 32, dim3(32, 8), 0, stream>>>(yt, bias, out, M);
}

// Round 3
// 809.100 us; speedup vs baseline: 1.0903x; 1.0903x over previous
//
#include <hip/hip_runtime.h>
#include <stdint.h>

#define NB 32          // batch size B (fixed by problem)
#define BIN_SHIFT 6    // 64 dst rows per bin
#define BIN_ROWS 64
#define NBINS_MAX 2048 // supports M <= 131072
#define FCHUNK 8192    // edges per hist/fill block (256 thr x 32)
#define SRC_BITS 18    // N < 262144 (problem: N = 100000)
#define SRC_MASK ((1u << SRC_BITS) - 1)

// ---------------------------------------------------------------------------
// x (B, N) -> xt (N, B): 32x32 LDS tile transpose, coalesced read and write.
// ---------------------------------------------------------------------------
__global__ void transpose_x_kernel(const float* __restrict__ x,
                                   float* __restrict__ xt, int N) {
    __shared__ float tile[32][33];  // +1 pad: avoid bank conflicts
    int n0 = blockIdx.x * 32;
    for (int i = threadIdx.y; i < 32; i += 8) {
        int n = n0 + threadIdx.x;
        tile[i][threadIdx.x] = (n < N) ? x[(size_t)i * N + n] : 0.f;
    }
    __syncthreads();
    for (int i = threadIdx.y; i < 32; i += 8) {
        int n = n0 + i;
        if (n < N) xt[(size_t)n * NB + threadIdx.x] = tile[threadIdx.x][i];
    }
}

// ---------------------------------------------------------------------------
// Per-bin histogram via per-block LDS histogram (one global atomic per
// nonzero (block,bin), not per edge).
// ---------------------------------------------------------------------------
__global__ void bin_hist(const int* __restrict__ dst,
                         int* __restrict__ binCnt, int nnz, int nbins) {
    __shared__ int lhist[NBINS_MAX];
    int t = threadIdx.x;
    for (int i = t; i < nbins; i += 256) lhist[i] = 0;
    __syncthreads();
    int e0 = blockIdx.x * FCHUNK;
#pragma unroll 4
    for (int k = 0; k < 32; ++k) {
        int e = e0 + k * 256 + t;
        if (e < nnz) atomicAdd(&lhist[dst[e] >> BIN_SHIFT], 1);
    }
    __syncthreads();
    for (int i = t; i < nbins; i += 256)
        if (lhist[i]) atomicAdd(&binCnt[i], lhist[i]);
}

// ---------------------------------------------------------------------------
// Exclusive scan of bin counts (single block, 1024 thr x 2 bins; nbins<=2048).
// binBase[nbins] = total. binCursor starts == binBase (fill claim pointers).
// ---------------------------------------------------------------------------
__global__ void bin_scan(const int* __restrict__ binCnt,
                         int* __restrict__ binBase,
                         int* __restrict__ binCursor, int nbins) {
    __shared__ int s[1024];
    int t = threadIdx.x;
    int i0 = t * 2, i1 = t * 2 + 1;
    int v0 = (i0 < nbins) ? binCnt[i0] : 0;
    int v1 = (i1 < nbins) ? binCnt[i1] : 0;
    int sum = v0 + v1;
    s[t] = sum;
    __syncthreads();
    for (int off = 1; off < 1024; off <<= 1) {
        int add = (t >= off) ? s[t - off] : 0;
        __syncthreads();
        s[t] += add;
        __syncthreads();
    }
    int run = s[t] - sum;  // exclusive prefix for this thread
    if (i0 < nbins) { binBase[i0] = run; binCursor[i0] = run; }
    run += v0;
    if (i1 < nbins) { binBase[i1] = run; binCursor[i1] = run; }
    if (t == 0) binBase[nbins] = s[1023];
}

// ---------------------------------------------------------------------------
// Binned fill: per-block LDS hist -> one cursor claim per (block,bin) ->
// ranked write. Same-bin edges from one block are CONTIGUOUS in csr, so
// scattered-line traffic is ~runs, not one 64B line per 8B edge.
// Entry: meta = (dst&63) << 18 | src  (src < 2^18), val bits.
// ---------------------------------------------------------------------------
__global__ void bin_fill(const int* __restrict__ src,
                         const int* __restrict__ dst,
                         const float* __restrict__ vals,
                         int* __restrict__ binCursor,
                         uint2* __restrict__ csr, int nnz, int nbins) {
    __shared__ int lhist[NBINS_MAX];
    __shared__ int lbase[NBINS_MAX];
    int t = threadIdx.x;
    int e0 = blockIdx.x * FCHUNK;
    for (int i = t; i < nbins; i += 256) lhist[i] = 0;
    __syncthreads();
#pragma unroll 4
    for (int k = 0; k < 32; ++k) {
        int e = e0 + k * 256 + t;
        if (e < nnz) atomicAdd(&lhist[dst[e] >> BIN_SHIFT], 1);
    }
    __syncthreads();
    for (int i = t; i < nbins; i += 256) {
        int c = lhist[i];
        lbase[i] = c ? atomicAdd(&binCursor[i], c) : 0;
        lhist[i] = 0;  // reuse as intra-block rank cursor
    }
    __syncthreads();
#pragma unroll 4
    for (int k = 0; k < 32; ++k) {
        int e = e0 + k * 256 + t;
        if (e < nnz) {
            int d = dst[e];            // L2-hot: already read in pass 1
            int bin = d >> BIN_SHIFT;
            int r = atomicAdd(&lhist[bin], 1);
            uint32_t meta = ((uint32_t)(d & (BIN_ROWS - 1)) << SRC_BITS) |
                            (uint32_t)src[e];
            csr[lbase[bin] + r] = make_uint2(meta, __float_as_uint(vals[e]));
        }
    }
}

// ---------------------------------------------------------------------------
// One block per 64-row bin: accumulate the bin's 64x32 output tile in LDS.
//  - csr stream: contiguous, uniform-per-halfwave 8B broadcast loads
//  - xt gather: 32 lanes cover the 128B line (coalesced, L3-resident)
//  - 16-deep pipeline: 16 gathers in flight per half-wave (MLP for latency)
//  - LDS atomicAdd: bank = lane -> max 2 lanes/bank = free
//  - flush: one coalesced 8KB store, no global atomics, no yt memset
// ---------------------------------------------------------------------------
__global__ __launch_bounds__(256) void bin_scatter(
        const int* __restrict__ binBase,
        const uint2* __restrict__ csr,
        const float* __restrict__ xt,
        float* __restrict__ yt, int M) {
    __shared__ float tile[BIN_ROWS * NB];  // 8 KB
    int t = threadIdx.x;
    int bin = blockIdx.x;
    for (int i = t * 4; i < BIN_ROWS * NB; i += 256 * 4)
        *(float4*)&tile[i] = make_float4(0.f, 0.f, 0.f, 0.f);
    __syncthreads();

    int start = binBase[bin];
    int end   = binBase[bin + 1];
    int g = t >> 5;       // half-wave id 0..7
    int b = t & 31;       // batch lane
    int cnt = end - start;
    int nch = cnt >> 4;   // full 16-edge chunks

    for (int c = g; c < nch; c += 8) {
        int base = start + (c << 4);
        uint2 e[16];
#pragma unroll
        for (int k = 0; k < 16; ++k) e[k] = csr[base + k];
        float xv[16];
#pragma unroll
        for (int k = 0; k < 16; ++k)
            xv[k] = xt[(size_t)(e[k].x & SRC_MASK) * NB + b];
#pragma unroll
        for (int k = 0; k < 16; ++k)
            atomicAdd(&tile[(e[k].x >> SRC_BITS) * NB + b],
                      __uint_as_float(e[k].y) * xv[k]);
    }
    // leftover (<16 edges)
    for (int j = start + (nch << 4) + g; j < end; j += 8) {
        uint2 e = csr[j];
        float xv = xt[(size_t)(e.x & SRC_MASK) * NB + b];
        atomicAdd(&tile[(e.x >> SRC_BITS) * NB + b],
                  __uint_as_float(e.y) * xv);
    }
    __syncthreads();

    size_t row0 = (size_t)bin * BIN_ROWS;
    int rows = min(BIN_ROWS, (int)(M - row0));
    float* dstp = yt + row0 * NB;
    int lim = rows * NB;  // multiple of 4
    for (int i = t * 4; i < lim; i += 256 * 4)
        *(float4*)&dstp[i] = *(float4*)&tile[i];
}

// ---------------------------------------------------------------------------
// yt (M, B) -> out (B, M), + bias: 32x32 LDS tile transpose.
// ---------------------------------------------------------------------------
__global__ void finalize_kernel(const float* __restrict__ yt,
                                const float* __restrict__ bias,
                                float* __restrict__ out, int M) {
    __shared__ float tile[32][33];
    int m0 = blockIdx.x * 32;
    for (int i = threadIdx.y; i < 32; i += 8) {
        int m = m0 + i;
        tile[i][threadIdx.x] = (m < M) ? yt[(size_t)m * NB + threadIdx.x] : 0.f;
    }
    __syncthreads();
    for (int i = threadIdx.y; i < 32; i += 8) {
        int m = m0 + threadIdx.x;
        if (m < M) out[(size_t)i * M + m] = tile[threadIdx.x][i] + bias[m];
    }
}

extern "C" void kernel_launch(void* const* d_in, const int* in_sizes, int n_in,
                              void* d_out, int out_size, void* d_ws, size_t ws_size,
                              hipStream_t stream) {
    const float* x       = (const float*)d_in[0];   // (B, N, 1) fp32
    const int*   indices = (const int*)  d_in[1];   // (2, NNZ) int32
    const float* vals    = (const float*)d_in[2];   // (NNZ,) fp32
    const float* bias    = (const float*)d_in[3];   // (M, 1) fp32

    float* out = (float*)d_out;                     // (B, M, 1) fp32

    int nnz = in_sizes[1] / 2;
    int N   = in_sizes[0] / NB;
    int M   = in_sizes[3];

    const int* src = indices;        // row 0
    const int* dst = indices + nnz;  // row 1

    int nbins = (M + BIN_ROWS - 1) >> BIN_SHIFT;   // 1563 for M=100000

    // workspace layout:
    //   xt        N*NB f32   (12.8 MB)
    //   yt        M*NB f32   (12.8 MB)
    //   binCnt    NBINS_MAX i32
    //   binBase   NBINS_MAX+1 i32
    //   binCursor NBINS_MAX i32
    //   csr       NNZ uint2  (25.6 MB)
    float* xt        = (float*)d_ws;
    float* yt        = xt + (size_t)N * NB;
    int*   binCnt    = (int*)(yt + (size_t)M * NB);
    int*   binBase   = binCnt + NBINS_MAX;
    int*   binCursor = binBase + NBINS_MAX + 1;
    uint2* csr       = (uint2*)(((uintptr_t)(binCursor + NBINS_MAX) + 15) &
                                ~(uintptr_t)15);

    transpose_x_kernel<<<(N + 31) / 32, dim3(32, 8), 0, stream>>>(x, xt, N);

    hipMemsetAsync(binCnt, 0, nbins * sizeof(int), stream);

    int fgrid = (nnz + FCHUNK - 1) / FCHUNK;  // 391
    bin_hist<<<fgrid, 256, 0, stream>>>(dst, binCnt, nnz, nbins);
    bin_scan<<<1, 1024, 0, stream>>>(binCnt, binBase, binCursor, nbins);
    bin_fill<<<fgrid, 256, 0, stream>>>(src, dst, vals, binCursor, csr, nnz, nbins);

    bin_scatter<<<nbins, 256, 0, stream>>>(binBase, csr, xt, yt, M);

    finalize_kernel<<<(M + 31) / 32, dim3(32, 8), 0, stream>>>(yt, bias, out, M);
}

// Round 4
// 303.118 us; speedup vs baseline: 2.9104x; 2.6693x over previous
//
#include <hip/hip_runtime.h>
#include <stdint.h>

#define NB 32          // batch size B (fixed by problem)
#define BIN_SHIFT 6    // 64 dst rows per bin
#define BIN_ROWS 64
#define NBINS_MAX 2048 // supports M <= 131072
#define FCHUNK 8192    // edges per hist/fill block (256 thr x 32)
#define SRC_BITS 18    // N < 262144 (problem: N = 100000)
#define SRC_MASK ((1u << SRC_BITS) - 1)

// ---------------------------------------------------------------------------
// x (B, N) -> xt (N, B): 32x32 LDS tile transpose, coalesced read and write.
// ---------------------------------------------------------------------------
__global__ void transpose_x_kernel(const float* __restrict__ x,
                                   float* __restrict__ xt, int N) {
    __shared__ float tile[32][33];  // +1 pad: avoid bank conflicts
    int n0 = blockIdx.x * 32;
    for (int i = threadIdx.y; i < 32; i += 8) {
        int n = n0 + threadIdx.x;
        tile[i][threadIdx.x] = (n < N) ? x[(size_t)i * N + n] : 0.f;
    }
    __syncthreads();
    for (int i = threadIdx.y; i < 32; i += 8) {
        int n = n0 + i;
        if (n < N) xt[(size_t)n * NB + threadIdx.x] = tile[threadIdx.x][i];
    }
}

// ---------------------------------------------------------------------------
// Per-bin histogram via per-block LDS histogram.
// ---------------------------------------------------------------------------
__global__ void bin_hist(const int* __restrict__ dst,
                         int* __restrict__ binCnt, int nnz, int nbins) {
    __shared__ int lhist[NBINS_MAX];
    int t = threadIdx.x;
    for (int i = t; i < nbins; i += 256) lhist[i] = 0;
    __syncthreads();
    int e0 = blockIdx.x * FCHUNK;
#pragma unroll 4
    for (int k = 0; k < 32; ++k) {
        int e = e0 + k * 256 + t;
        if (e < nnz) atomicAdd(&lhist[dst[e] >> BIN_SHIFT], 1);
    }
    __syncthreads();
    for (int i = t; i < nbins; i += 256)
        if (lhist[i]) atomicAdd(&binCnt[i], lhist[i]);
}

// ---------------------------------------------------------------------------
// Exclusive scan of bin counts (single block, 1024 thr x 2; nbins <= 2048).
// ---------------------------------------------------------------------------
__global__ void bin_scan(const int* __restrict__ binCnt,
                         int* __restrict__ binBase,
                         int* __restrict__ binCursor, int nbins) {
    __shared__ int s[1024];
    int t = threadIdx.x;
    int i0 = t * 2, i1 = t * 2 + 1;
    int v0 = (i0 < nbins) ? binCnt[i0] : 0;
    int v1 = (i1 < nbins) ? binCnt[i1] : 0;
    int sum = v0 + v1;
    s[t] = sum;
    __syncthreads();
    for (int off = 1; off < 1024; off <<= 1) {
        int add = (t >= off) ? s[t - off] : 0;
        __syncthreads();
        s[t] += add;
        __syncthreads();
    }
    int run = s[t] - sum;
    if (i0 < nbins) { binBase[i0] = run; binCursor[i0] = run; }
    run += v0;
    if (i1 < nbins) { binBase[i1] = run; binCursor[i1] = run; }
    if (t == 0) binBase[nbins] = s[1023];
}

// ---------------------------------------------------------------------------
// Binned fill: per-block LDS hist -> one cursor claim per (block,bin) ->
// ranked write. Same-bin edges from one block are CONTIGUOUS in csr.
// Entry: meta = (dst&63) << 18 | src, val bits.
// ---------------------------------------------------------------------------
__global__ void bin_fill(const int* __restrict__ src,
                         const int* __restrict__ dst,
                         const float* __restrict__ vals,
                         int* __restrict__ binCursor,
                         uint2* __restrict__ csr, int nnz, int nbins) {
    __shared__ int lhist[NBINS_MAX];
    __shared__ int lbase[NBINS_MAX];
    int t = threadIdx.x;
    int e0 = blockIdx.x * FCHUNK;
    for (int i = t; i < nbins; i += 256) lhist[i] = 0;
    __syncthreads();
#pragma unroll 4
    for (int k = 0; k < 32; ++k) {
        int e = e0 + k * 256 + t;
        if (e < nnz) atomicAdd(&lhist[dst[e] >> BIN_SHIFT], 1);
    }
    __syncthreads();
    for (int i = t; i < nbins; i += 256) {
        int c = lhist[i];
        lbase[i] = c ? atomicAdd(&binCursor[i], c) : 0;
        lhist[i] = 0;  // reuse as intra-block rank cursor
    }
    __syncthreads();
#pragma unroll 4
    for (int k = 0; k < 32; ++k) {
        int e = e0 + k * 256 + t;
        if (e < nnz) {
            int d = dst[e];
            int bin = d >> BIN_SHIFT;
            int r = atomicAdd(&lhist[bin], 1);
            uint32_t meta = ((uint32_t)(d & (BIN_ROWS - 1)) << SRC_BITS) |
                            (uint32_t)src[e];
            csr[lbase[bin] + r] = make_uint2(meta, __float_as_uint(vals[e]));
        }
    }
}

// ---------------------------------------------------------------------------
// Per-bin counting sort by row (streaming, no staging, no size cap):
// pass 1: LDS hist of 64 rows; scan; write rowPtr.
// pass 2: re-read bin edges, claim rank via LDS cursor, write to sorted
//         position. All writes land in the bin's own contiguous ~16KB
//         window -> L2-resident, coalesced writeback.
// ---------------------------------------------------------------------------
__global__ void row_sort(const int* __restrict__ binBase,
                         const uint2* __restrict__ csr,
                         uint2* __restrict__ csr2,
                         int* __restrict__ rowPtr,
                         int M, int nnz, int nbins) {
    __shared__ int rowCnt[BIN_ROWS];
    __shared__ int rowOff[BIN_ROWS];  // exclusive base, then fill cursor
    int t = threadIdx.x;
    int bin = blockIdx.x;
    int start = binBase[bin];
    int end   = binBase[bin + 1];
    if (t < BIN_ROWS) rowCnt[t] = 0;
    __syncthreads();
    for (int j = start + t; j < end; j += 256) {
        uint2 e = csr[j];
        atomicAdd(&rowCnt[e.x >> SRC_BITS], 1);
    }
    __syncthreads();
    if (t == 0) {
        int run = 0;
#pragma unroll
        for (int r = 0; r < BIN_ROWS; ++r) { rowOff[r] = run; run += rowCnt[r]; }
    }
    __syncthreads();
    if (t < BIN_ROWS) {
        int m = bin * BIN_ROWS + t;
        if (m < M) rowPtr[m] = start + rowOff[t];
    }
    if (bin == nbins - 1 && t == 0) rowPtr[M] = nnz;
    __syncthreads();  // rowPtr reads of rowOff done before cursor mutation
    for (int j = start + t; j < end; j += 256) {
        uint2 e = csr[j];
        int r = e.x >> SRC_BITS;
        int p = atomicAdd(&rowOff[r], 1);
        csr2[start + p] = e;
    }
}

// ---------------------------------------------------------------------------
// Atomic-free gather: one half-wave (32 lanes = 32 batch cols) per output
// row m. Contiguous edge list [rowPtr[m], rowPtr[m+1]), register
// accumulation, 8-deep unrolled load pipeline (no atomicrmw in the loop ->
// compiler free to keep 8 gathers in flight), one coalesced 128B store.
// ---------------------------------------------------------------------------
__global__ void row_gather(const int* __restrict__ rowPtr,
                           const uint2* __restrict__ csr2,
                           const float* __restrict__ xt,
                           float* __restrict__ yt, int M) {
    int t = threadIdx.x;
    int g = t >> 5;       // half-wave id 0..7
    int b = t & 31;       // batch lane
    int m = blockIdx.x * 8 + g;
    if (m >= M) return;
    int j   = rowPtr[m];
    int end = rowPtr[m + 1];
    float acc0 = 0.f, acc1 = 0.f;
    for (; j + 8 <= end; j += 8) {
        uint2 e0 = csr2[j + 0];
        uint2 e1 = csr2[j + 1];
        uint2 e2 = csr2[j + 2];
        uint2 e3 = csr2[j + 3];
        uint2 e4 = csr2[j + 4];
        uint2 e5 = csr2[j + 5];
        uint2 e6 = csr2[j + 6];
        uint2 e7 = csr2[j + 7];
        float x0 = xt[(size_t)(e0.x & SRC_MASK) * NB + b];
        float x1 = xt[(size_t)(e1.x & SRC_MASK) * NB + b];
        float x2 = xt[(size_t)(e2.x & SRC_MASK) * NB + b];
        float x3 = xt[(size_t)(e3.x & SRC_MASK) * NB + b];
        float x4 = xt[(size_t)(e4.x & SRC_MASK) * NB + b];
        float x5 = xt[(size_t)(e5.x & SRC_MASK) * NB + b];
        float x6 = xt[(size_t)(e6.x & SRC_MASK) * NB + b];
        float x7 = xt[(size_t)(e7.x & SRC_MASK) * NB + b];
        acc0 = fmaf(__uint_as_float(e0.y), x0, acc0);
        acc1 = fmaf(__uint_as_float(e1.y), x1, acc1);
        acc0 = fmaf(__uint_as_float(e2.y), x2, acc0);
        acc1 = fmaf(__uint_as_float(e3.y), x3, acc1);
        acc0 = fmaf(__uint_as_float(e4.y), x4, acc0);
        acc1 = fmaf(__uint_as_float(e5.y), x5, acc1);
        acc0 = fmaf(__uint_as_float(e6.y), x6, acc0);
        acc1 = fmaf(__uint_as_float(e7.y), x7, acc1);
    }
    for (; j < end; ++j) {
        uint2 e = csr2[j];
        acc0 = fmaf(__uint_as_float(e.y),
                    xt[(size_t)(e.x & SRC_MASK) * NB + b], acc0);
    }
    yt[(size_t)m * NB + b] = acc0 + acc1;
}

// ---------------------------------------------------------------------------
// yt (M, B) -> out (B, M), + bias: 32x32 LDS tile transpose.
// ---------------------------------------------------------------------------
__global__ void finalize_kernel(const float* __restrict__ yt,
                                const float* __restrict__ bias,
                                float* __restrict__ out, int M) {
    __shared__ float tile[32][33];
    int m0 = blockIdx.x * 32;
    for (int i = threadIdx.y; i < 32; i += 8) {
        int m = m0 + i;
        tile[i][threadIdx.x] = (m < M) ? yt[(size_t)m * NB + threadIdx.x] : 0.f;
    }
    __syncthreads();
    for (int i = threadIdx.y; i < 32; i += 8) {
        int m = m0 + threadIdx.x;
        if (m < M) out[(size_t)i * M + m] = tile[threadIdx.x][i] + bias[m];
    }
}

// ---------------------------------------------------------------------------
// Fallback (verified round-0 path): global-atomic scatter. Used only if
// ws_size can't hold the CSR buffers.
// ---------------------------------------------------------------------------
__global__ void scatter_kernel(const int* __restrict__ src,
                               const int* __restrict__ dst,
                               const float* __restrict__ vals,
                               const float* __restrict__ xt,
                               float* __restrict__ yt, int nnz) {
    long long tid = (long long)blockIdx.x * blockDim.x + threadIdx.x;
    int e = (int)(tid >> 5);
    if (e >= nnz) return;
    int b = (int)(tid & 31);
    atomicAdd(&yt[(size_t)dst[e] * NB + b], vals[e] * xt[(size_t)src[e] * NB + b]);
}

extern "C" void kernel_launch(void* const* d_in, const int* in_sizes, int n_in,
                              void* d_out, int out_size, void* d_ws, size_t ws_size,
                              hipStream_t stream) {
    const float* x       = (const float*)d_in[0];   // (B, N, 1) fp32
    const int*   indices = (const int*)  d_in[1];   // (2, NNZ) int32
    const float* vals    = (const float*)d_in[2];   // (NNZ,) fp32
    const float* bias    = (const float*)d_in[3];   // (M, 1) fp32

    float* out = (float*)d_out;                     // (B, M, 1) fp32

    int nnz = in_sizes[1] / 2;
    int N   = in_sizes[0] / NB;
    int M   = in_sizes[3];

    const int* src = indices;        // row 0
    const int* dst = indices + nnz;  // row 1

    int nbins = (M + BIN_ROWS - 1) >> BIN_SHIFT;   // 1563 for M=100000

    // workspace layout (primary path):
    //   xt        N*NB f32        (12.8 MB)
    //   yt        M*NB f32        (12.8 MB)
    //   binCnt    NBINS_MAX i32
    //   binBase   NBINS_MAX+1 i32
    //   binCursor NBINS_MAX i32
    //   rowPtr    M+1 i32         (0.4 MB)
    //   csr       NNZ uint2       (25.6 MB)
    //   csr2      NNZ uint2       (25.6 MB)
    float* xt        = (float*)d_ws;
    float* yt        = xt + (size_t)N * NB;
    int*   binCnt    = (int*)(yt + (size_t)M * NB);
    int*   binBase   = binCnt + NBINS_MAX;
    int*   binCursor = binBase + NBINS_MAX + 1;
    int*   rowPtr    = binCursor + NBINS_MAX;
    uint2* csr       = (uint2*)(((uintptr_t)(rowPtr + M + 1) + 15) &
                                ~(uintptr_t)15);
    uint2* csr2      = csr + nnz;

    size_t need = (size_t)((char*)(csr2 + nnz) - (char*)d_ws);

    transpose_x_kernel<<<(N + 31) / 32, dim3(32, 8), 0, stream>>>(x, xt, N);

    if (ws_size >= need) {
        hipMemsetAsync(binCnt, 0, nbins * sizeof(int), stream);

        int fgrid = (nnz + FCHUNK - 1) / FCHUNK;  // 391
        bin_hist<<<fgrid, 256, 0, stream>>>(dst, binCnt, nnz, nbins);
        bin_scan<<<1, 1024, 0, stream>>>(binCnt, binBase, binCursor, nbins);
        bin_fill<<<fgrid, 256, 0, stream>>>(src, dst, vals, binCursor, csr,
                                            nnz, nbins);
        row_sort<<<nbins, 256, 0, stream>>>(binBase, csr, csr2, rowPtr,
                                            M, nnz, nbins);
        row_gather<<<(M + 7) / 8, 256, 0, stream>>>(rowPtr, csr2, xt, yt, M);
    } else {
        // fallback: round-0 verified atomic path (needs only xt + yt)
        hipMemsetAsync(yt, 0, (size_t)M * NB * sizeof(float), stream);
        long long pairs = (long long)nnz * NB;
        int grid = (int)((pairs + 255) / 256);
        scatter_kernel<<<grid, 256, 0, stream>>>(src, dst, vals, xt, yt, nnz);
    }

    finalize_kernel<<<(M + 31) / 32, dim3(32, 8), 0, stream>>>(yt, bias, out, M);
}

// Round 5
// 258.231 us; speedup vs baseline: 3.4163x; 1.1738x over previous
//
#include <hip/hip_runtime.h>
#include <stdint.h>

#define NB 32          // batch size B (fixed by problem)
#define BIN_SHIFT 6    // 64 dst rows per bin
#define BIN_ROWS 64
#define NBINS_MAX 2048 // supports M <= 131072
#define FCHUNK 8192    // edges per hist/fill block
#define FTHREADS 512   // threads for hist/fill (occupancy: 8 waves/block)
#define SRC_BITS 18    // N < 262144 (problem: N = 100000)
#define SRC_MASK ((1u << SRC_BITS) - 1)
#define LCAP 2560      // LDS sort capacity per bin (mean 2048 + 11 sigma)

// ---------------------------------------------------------------------------
// x (B, N) -> xt (N, B): 32x32 LDS tile transpose, coalesced read and write.
// ---------------------------------------------------------------------------
__global__ void transpose_x_kernel(const float* __restrict__ x,
                                   float* __restrict__ xt, int N) {
    __shared__ float tile[32][33];  // +1 pad: avoid bank conflicts
    int n0 = blockIdx.x * 32;
    for (int i = threadIdx.y; i < 32; i += 8) {
        int n = n0 + threadIdx.x;
        tile[i][threadIdx.x] = (n < N) ? x[(size_t)i * N + n] : 0.f;
    }
    __syncthreads();
    for (int i = threadIdx.y; i < 32; i += 8) {
        int n = n0 + i;
        if (n < N) xt[(size_t)n * NB + threadIdx.x] = tile[threadIdx.x][i];
    }
}

// ---------------------------------------------------------------------------
// Per-bin histogram via per-block LDS histogram.
// ---------------------------------------------------------------------------
__global__ void bin_hist(const int* __restrict__ dst,
                         int* __restrict__ binCnt, int nnz, int nbins) {
    __shared__ int lhist[NBINS_MAX];
    int t = threadIdx.x;
    for (int i = t; i < nbins; i += FTHREADS) lhist[i] = 0;
    __syncthreads();
    int e0 = blockIdx.x * FCHUNK;
#pragma unroll 4
    for (int k = 0; k < FCHUNK / FTHREADS; ++k) {
        int e = e0 + k * FTHREADS + t;
        if (e < nnz) atomicAdd(&lhist[dst[e] >> BIN_SHIFT], 1);
    }
    __syncthreads();
    for (int i = t; i < nbins; i += FTHREADS)
        if (lhist[i]) atomicAdd(&binCnt[i], lhist[i]);
}

// ---------------------------------------------------------------------------
// Exclusive scan of bin counts (single block, 1024 thr x 2; nbins <= 2048).
// ---------------------------------------------------------------------------
__global__ void bin_scan(const int* __restrict__ binCnt,
                         int* __restrict__ binBase,
                         int* __restrict__ binCursor, int nbins) {
    __shared__ int s[1024];
    int t = threadIdx.x;
    int i0 = t * 2, i1 = t * 2 + 1;
    int v0 = (i0 < nbins) ? binCnt[i0] : 0;
    int v1 = (i1 < nbins) ? binCnt[i1] : 0;
    int sum = v0 + v1;
    s[t] = sum;
    __syncthreads();
    for (int off = 1; off < 1024; off <<= 1) {
        int add = (t >= off) ? s[t - off] : 0;
        __syncthreads();
        s[t] += add;
        __syncthreads();
    }
    int run = s[t] - sum;
    if (i0 < nbins) { binBase[i0] = run; binCursor[i0] = run; }
    run += v0;
    if (i1 < nbins) { binBase[i1] = run; binCursor[i1] = run; }
    if (t == 0) binBase[nbins] = s[1023];
}

// ---------------------------------------------------------------------------
// Binned fill: per-block LDS hist -> one cursor claim per (block,bin) ->
// ranked write. Same-bin edges from one block are CONTIGUOUS in csr.
// Entry: meta = (dst&63) << 18 | src, val bits.
// 512 threads: write traffic depends only on grid size (runs = fgrid x nbins),
// so more waves/block = more latency hiding at equal WRITE_SIZE.
// ---------------------------------------------------------------------------
__global__ void bin_fill(const int* __restrict__ src,
                         const int* __restrict__ dst,
                         const float* __restrict__ vals,
                         int* __restrict__ binCursor,
                         uint2* __restrict__ csr, int nnz, int nbins) {
    __shared__ int lhist[NBINS_MAX];
    __shared__ int lbase[NBINS_MAX];
    int t = threadIdx.x;
    int e0 = blockIdx.x * FCHUNK;
    for (int i = t; i < nbins; i += FTHREADS) lhist[i] = 0;
    __syncthreads();
#pragma unroll 4
    for (int k = 0; k < FCHUNK / FTHREADS; ++k) {
        int e = e0 + k * FTHREADS + t;
        if (e < nnz) atomicAdd(&lhist[dst[e] >> BIN_SHIFT], 1);
    }
    __syncthreads();
    for (int i = t; i < nbins; i += FTHREADS) {
        int c = lhist[i];
        lbase[i] = c ? atomicAdd(&binCursor[i], c) : 0;
        lhist[i] = 0;  // reuse as intra-block rank cursor
    }
    __syncthreads();
#pragma unroll 4
    for (int k = 0; k < FCHUNK / FTHREADS; ++k) {
        int e = e0 + k * FTHREADS + t;
        if (e < nnz) {
            int d = dst[e];
            int bin = d >> BIN_SHIFT;
            int r = atomicAdd(&lhist[bin], 1);
            uint32_t meta = ((uint32_t)(d & (BIN_ROWS - 1)) << SRC_BITS) |
                            (uint32_t)src[e];
            csr[lbase[bin] + r] = make_uint2(meta, __float_as_uint(vals[e]));
        }
    }
}

// ---------------------------------------------------------------------------
// Fused sort + gather, one block per 64-row bin:
//  1. counting-sort the bin's edges INTO LDS (hist -> scan -> LDS scatter);
//     the bin window (avg 2048 edges = 16 KB) fits LCAP = 2560 with 11-sigma
//     margin for this distribution; oversized bins take a correct (slower)
//     global-scan fallback.
//  2. each half-wave (32 lanes = 32 batch cols) gathers its rows from the
//     LDS-sorted list: pure register accumulation, 8-deep load pipeline,
//     NO atomics in the hot loop, one coalesced 128B store per row.
// Deletes csr2 (25.6 MB HBM write + read), rowPtr, and a kernel launch.
// ---------------------------------------------------------------------------
__global__ __launch_bounds__(256) void sort_gather(
        const int* __restrict__ binBase,
        const uint2* __restrict__ csr,
        const float* __restrict__ xt,
        float* __restrict__ yt, int M) {
    __shared__ uint2 sorted[LCAP];     // 20 KB
    __shared__ int rowCnt[BIN_ROWS];
    __shared__ int rowOff[BIN_ROWS];
    int t = threadIdx.x;
    int bin = blockIdx.x;
    int start = binBase[bin];
    int end   = binBase[bin + 1];
    int cnt   = end - start;
    int g = t >> 5;   // half-wave id 0..7
    int b = t & 31;   // batch lane

    if (cnt <= LCAP) {
        if (t < BIN_ROWS) rowCnt[t] = 0;
        __syncthreads();
        for (int j = start + t; j < end; j += 256)
            atomicAdd(&rowCnt[csr[j].x >> SRC_BITS], 1);
        __syncthreads();
        if (t == 0) {
            int run = 0;
#pragma unroll
            for (int r = 0; r < BIN_ROWS; ++r) {
                rowOff[r] = run;
                run += rowCnt[r];
            }
        }
        __syncthreads();
        for (int j = start + t; j < end; j += 256) {
            uint2 e = csr[j];   // L2-hot (read in hist pass)
            int p = atomicAdd(&rowOff[e.x >> SRC_BITS], 1);
            sorted[p] = e;
        }
        __syncthreads();
        // after scatter, rowOff[r] == end of row r; start = end - rowCnt[r]
        for (int r = g; r < BIN_ROWS; r += 8) {
            int m = bin * BIN_ROWS + r;
            if (m >= M) break;
            int jend = rowOff[r];
            int jj   = jend - rowCnt[r];
            float acc0 = 0.f, acc1 = 0.f;
            for (; jj + 8 <= jend; jj += 8) {
                uint2 e0 = sorted[jj + 0];
                uint2 e1 = sorted[jj + 1];
                uint2 e2 = sorted[jj + 2];
                uint2 e3 = sorted[jj + 3];
                uint2 e4 = sorted[jj + 4];
                uint2 e5 = sorted[jj + 5];
                uint2 e6 = sorted[jj + 6];
                uint2 e7 = sorted[jj + 7];
                float x0 = xt[(size_t)(e0.x & SRC_MASK) * NB + b];
                float x1 = xt[(size_t)(e1.x & SRC_MASK) * NB + b];
                float x2 = xt[(size_t)(e2.x & SRC_MASK) * NB + b];
                float x3 = xt[(size_t)(e3.x & SRC_MASK) * NB + b];
                float x4 = xt[(size_t)(e4.x & SRC_MASK) * NB + b];
                float x5 = xt[(size_t)(e5.x & SRC_MASK) * NB + b];
                float x6 = xt[(size_t)(e6.x & SRC_MASK) * NB + b];
                float x7 = xt[(size_t)(e7.x & SRC_MASK) * NB + b];
                acc0 = fmaf(__uint_as_float(e0.y), x0, acc0);
                acc1 = fmaf(__uint_as_float(e1.y), x1, acc1);
                acc0 = fmaf(__uint_as_float(e2.y), x2, acc0);
                acc1 = fmaf(__uint_as_float(e3.y), x3, acc1);
                acc0 = fmaf(__uint_as_float(e4.y), x4, acc0);
                acc1 = fmaf(__uint_as_float(e5.y), x5, acc1);
                acc0 = fmaf(__uint_as_float(e6.y), x6, acc0);
                acc1 = fmaf(__uint_as_float(e7.y), x7, acc1);
            }
            for (; jj < jend; ++jj) {
                uint2 e = sorted[jj];
                acc0 = fmaf(__uint_as_float(e.y),
                            xt[(size_t)(e.x & SRC_MASK) * NB + b], acc0);
            }
            yt[(size_t)m * NB + b] = acc0 + acc1;
        }
    } else {
        // robust fallback for oversized bins: per-row scan of the bin window
        // (window is L2-resident; only triggered by pathological skew)
        for (int r = g; r < BIN_ROWS; r += 8) {
            int m = bin * BIN_ROWS + r;
            if (m >= M) break;
            float acc = 0.f;
            for (int j = start; j < end; ++j) {
                uint2 e = csr[j];
                if ((int)(e.x >> SRC_BITS) == r)
                    acc = fmaf(__uint_as_float(e.y),
                               xt[(size_t)(e.x & SRC_MASK) * NB + b], acc);
            }
            yt[(size_t)m * NB + b] = acc;
        }
    }
}

// ---------------------------------------------------------------------------
// yt (M, B) -> out (B, M), + bias: 32x32 LDS tile transpose.
// ---------------------------------------------------------------------------
__global__ void finalize_kernel(const float* __restrict__ yt,
                                const float* __restrict__ bias,
                                float* __restrict__ out, int M) {
    __shared__ float tile[32][33];
    int m0 = blockIdx.x * 32;
    for (int i = threadIdx.y; i < 32; i += 8) {
        int m = m0 + i;
        tile[i][threadIdx.x] = (m < M) ? yt[(size_t)m * NB + threadIdx.x] : 0.f;
    }
    __syncthreads();
    for (int i = threadIdx.y; i < 32; i += 8) {
        int m = m0 + threadIdx.x;
        if (m < M) out[(size_t)i * M + m] = tile[threadIdx.x][i] + bias[m];
    }
}

// ---------------------------------------------------------------------------
// Fallback (verified round-0 path): global-atomic scatter. Used only if
// ws_size can't hold the CSR buffers.
// ---------------------------------------------------------------------------
__global__ void scatter_kernel(const int* __restrict__ src,
                               const int* __restrict__ dst,
                               const float* __restrict__ vals,
                               const float* __restrict__ xt,
                               float* __restrict__ yt, int nnz) {
    long long tid = (long long)blockIdx.x * blockDim.x + threadIdx.x;
    int e = (int)(tid >> 5);
    if (e >= nnz) return;
    int b = (int)(tid & 31);
    atomicAdd(&yt[(size_t)dst[e] * NB + b], vals[e] * xt[(size_t)src[e] * NB + b]);
}

extern "C" void kernel_launch(void* const* d_in, const int* in_sizes, int n_in,
                              void* d_out, int out_size, void* d_ws, size_t ws_size,
                              hipStream_t stream) {
    const float* x       = (const float*)d_in[0];   // (B, N, 1) fp32
    const int*   indices = (const int*)  d_in[1];   // (2, NNZ) int32
    const float* vals    = (const float*)d_in[2];   // (NNZ,) fp32
    const float* bias    = (const float*)d_in[3];   // (M, 1) fp32

    float* out = (float*)d_out;                     // (B, M, 1) fp32

    int nnz = in_sizes[1] / 2;
    int N   = in_sizes[0] / NB;
    int M   = in_sizes[3];

    const int* src = indices;        // row 0
    const int* dst = indices + nnz;  // row 1

    int nbins = (M + BIN_ROWS - 1) >> BIN_SHIFT;   // 1563 for M=100000

    // workspace layout (primary path, ~52 MB):
    //   xt        N*NB f32        (12.8 MB)
    //   yt        M*NB f32        (12.8 MB)
    //   binCnt    NBINS_MAX i32
    //   binBase   NBINS_MAX+1 i32
    //   binCursor NBINS_MAX i32
    //   csr       NNZ uint2       (25.6 MB)
    float* xt        = (float*)d_ws;
    float* yt        = xt + (size_t)N * NB;
    int*   binCnt    = (int*)(yt + (size_t)M * NB);
    int*   binBase   = binCnt + NBINS_MAX;
    int*   binCursor = binBase + NBINS_MAX + 1;
    uint2* csr       = (uint2*)(((uintptr_t)(binCursor + NBINS_MAX) + 15) &
                                ~(uintptr_t)15);

    size_t need = (size_t)((char*)(csr + nnz) - (char*)d_ws);

    transpose_x_kernel<<<(N + 31) / 32, dim3(32, 8), 0, stream>>>(x, xt, N);

    if (ws_size >= need) {
        hipMemsetAsync(binCnt, 0, nbins * sizeof(int), stream);

        int fgrid = (nnz + FCHUNK - 1) / FCHUNK;  // 391
        bin_hist<<<fgrid, FTHREADS, 0, stream>>>(dst, binCnt, nnz, nbins);
        bin_scan<<<1, 1024, 0, stream>>>(binCnt, binBase, binCursor, nbins);
        bin_fill<<<fgrid, FTHREADS, 0, stream>>>(src, dst, vals, binCursor,
                                                 csr, nnz, nbins);
        sort_gather<<<nbins, 256, 0, stream>>>(binBase, csr, xt, yt, M);
    } else {
        // fallback: round-0 verified atomic path (needs only xt + yt)
        hipMemsetAsync(yt, 0, (size_t)M * NB * sizeof(float), stream);
        long long pairs = (long long)nnz * NB;
        int grid = (int)((pairs + 255) / 256);
        scatter_kernel<<<grid, 256, 0, stream>>>(src, dst, vals, xt, yt, nnz);
    }

    finalize_kernel<<<(M + 31) / 32, dim3(32, 8), 0, stream>>>(yt, bias, out, M);
}

// Round 6
// 249.606 us; speedup vs baseline: 3.5343x; 1.0346x over previous
//
#include <hip/hip_runtime.h>
#include <stdint.h>

#define NB 32          // batch size B (fixed by problem)
#define BIN_SHIFT 6    // 64 dst rows per bin
#define BIN_ROWS 64
#define NBINS_MAX 2048 // supports M <= 131072
#define FCHUNK 8192    // edges per fill block
#define FTHREADS 1024  // fill threads: 16 waves/block, 16KB LDS -> ~24 waves/CU
#define SRC_BITS 18    // N < 262144 (problem: N = 100000)
#define SRC_MASK ((1u << SRC_BITS) - 1)
#define CAP 3072       // fixed bin capacity: mean 2048 + 22 sigma

// ---------------------------------------------------------------------------
// x (B, N) -> xt (N, B): 32x32 LDS tile transpose, coalesced read and write.
// ---------------------------------------------------------------------------
__global__ void transpose_x_kernel(const float* __restrict__ x,
                                   float* __restrict__ xt, int N) {
    __shared__ float tile[32][33];  // +1 pad: avoid bank conflicts
    int n0 = blockIdx.x * 32;
    for (int i = threadIdx.y; i < 32; i += 8) {
        int n = n0 + threadIdx.x;
        tile[i][threadIdx.x] = (n < N) ? x[(size_t)i * N + n] : 0.f;
    }
    __syncthreads();
    for (int i = threadIdx.y; i < 32; i += 8) {
        int n = n0 + i;
        if (n < N) xt[(size_t)n * NB + threadIdx.x] = tile[threadIdx.x][i];
    }
}

// ---------------------------------------------------------------------------
// binCursor[i] = i*CAP (fixed-capacity bins — no global hist/scan needed).
// ---------------------------------------------------------------------------
__global__ void init_cursor(int* __restrict__ binCursor,
                            int* __restrict__ ovCount, int nbins) {
    int i = blockIdx.x * blockDim.x + threadIdx.x;
    if (i < nbins) binCursor[i] = i * CAP;
    if (i == 0) *ovCount = 0;
}

// ---------------------------------------------------------------------------
// Binned fill: per-block LDS hist -> one cursor claim per (block,bin) ->
// ranked write. Same-bin edges from one block are CONTIGUOUS in csr.
// Entry: meta = (dst&63) << 18 | src, val bits.
// Fixed-cap bins: slots beyond the bin's cap spill edge-ids to ovList
// (statistically never: cap = mean + 22 sigma), fixed up after gather.
// ---------------------------------------------------------------------------
__global__ void bin_fill(const int* __restrict__ src,
                         const int* __restrict__ dst,
                         const float* __restrict__ vals,
                         int* __restrict__ binCursor,
                         uint2* __restrict__ csr,
                         int* __restrict__ ovCount,
                         int* __restrict__ ovList,
                         int nnz, int nbins) {
    __shared__ int lhist[NBINS_MAX];
    __shared__ int lbase[NBINS_MAX];
    int t = threadIdx.x;
    int e0 = blockIdx.x * FCHUNK;
    for (int i = t; i < nbins; i += FTHREADS) lhist[i] = 0;
    __syncthreads();
#pragma unroll 4
    for (int k = 0; k < FCHUNK / FTHREADS; ++k) {
        int e = e0 + k * FTHREADS + t;
        if (e < nnz) atomicAdd(&lhist[dst[e] >> BIN_SHIFT], 1);
    }
    __syncthreads();
    for (int i = t; i < nbins; i += FTHREADS) {
        int c = lhist[i];
        lbase[i] = c ? atomicAdd(&binCursor[i], c) : 0;
        lhist[i] = 0;  // reuse as intra-block rank cursor
    }
    __syncthreads();
#pragma unroll 4
    for (int k = 0; k < FCHUNK / FTHREADS; ++k) {
        int e = e0 + k * FTHREADS + t;
        if (e < nnz) {
            int d = dst[e];
            int bin = d >> BIN_SHIFT;
            int r = atomicAdd(&lhist[bin], 1);
            int slot = lbase[bin] + r;
            if (slot < (bin + 1) * CAP) {
                uint32_t meta = ((uint32_t)(d & (BIN_ROWS - 1)) << SRC_BITS) |
                                (uint32_t)src[e];
                csr[slot] = make_uint2(meta, __float_as_uint(vals[e]));
            } else {
                int op = atomicAdd(ovCount, 1);
                ovList[op] = e;   // ovList sized nnz: can never overflow
            }
        }
    }
}

// ---------------------------------------------------------------------------
// Fused sort + gather, one block per 64-row bin:
//  1. counting-sort the bin's edges INTO LDS (hist -> scan -> LDS scatter);
//     fill guarantees cnt <= CAP.
//  2. each half-wave (32 lanes = 32 batch cols) gathers its rows from the
//     LDS-sorted list: pure register accumulation, 8-deep load pipeline,
//     NO atomics in the hot loop, one coalesced 128B store per row.
// ---------------------------------------------------------------------------
__global__ __launch_bounds__(256) void sort_gather(
        const int* __restrict__ binCursor,
        const uint2* __restrict__ csr,
        const float* __restrict__ xt,
        float* __restrict__ yt, int M) {
    __shared__ uint2 sorted[CAP];      // 24 KB
    __shared__ int rowCnt[BIN_ROWS];
    __shared__ int rowOff[BIN_ROWS];
    int t = threadIdx.x;
    int bin = blockIdx.x;
    int start = bin * CAP;
    int cnt   = min(binCursor[bin] - start, CAP);
    int end   = start + cnt;
    int g = t >> 5;   // half-wave id 0..7
    int b = t & 31;   // batch lane

    if (t < BIN_ROWS) rowCnt[t] = 0;
    __syncthreads();
    for (int j = start + t; j < end; j += 256)
        atomicAdd(&rowCnt[csr[j].x >> SRC_BITS], 1);
    __syncthreads();
    if (t == 0) {
        int run = 0;
#pragma unroll
        for (int r = 0; r < BIN_ROWS; ++r) {
            rowOff[r] = run;
            run += rowCnt[r];
        }
    }
    __syncthreads();
    for (int j = start + t; j < end; j += 256) {
        uint2 e = csr[j];   // L2-hot (read in hist pass)
        int p = atomicAdd(&rowOff[e.x >> SRC_BITS], 1);
        sorted[p] = e;
    }
    __syncthreads();
    // after scatter, rowOff[r] == end of row r; start = end - rowCnt[r]
    for (int r = g; r < BIN_ROWS; r += 8) {
        int m = bin * BIN_ROWS + r;
        if (m >= M) break;
        int jend = rowOff[r];
        int jj   = jend - rowCnt[r];
        float acc0 = 0.f, acc1 = 0.f;
        for (; jj + 8 <= jend; jj += 8) {
            uint2 e0 = sorted[jj + 0];
            uint2 e1 = sorted[jj + 1];
            uint2 e2 = sorted[jj + 2];
            uint2 e3 = sorted[jj + 3];
            uint2 e4 = sorted[jj + 4];
            uint2 e5 = sorted[jj + 5];
            uint2 e6 = sorted[jj + 6];
            uint2 e7 = sorted[jj + 7];
            float x0 = xt[(size_t)(e0.x & SRC_MASK) * NB + b];
            float x1 = xt[(size_t)(e1.x & SRC_MASK) * NB + b];
            float x2 = xt[(size_t)(e2.x & SRC_MASK) * NB + b];
            float x3 = xt[(size_t)(e3.x & SRC_MASK) * NB + b];
            float x4 = xt[(size_t)(e4.x & SRC_MASK) * NB + b];
            float x5 = xt[(size_t)(e5.x & SRC_MASK) * NB + b];
            float x6 = xt[(size_t)(e6.x & SRC_MASK) * NB + b];
            float x7 = xt[(size_t)(e7.x & SRC_MASK) * NB + b];
            acc0 = fmaf(__uint_as_float(e0.y), x0, acc0);
            acc1 = fmaf(__uint_as_float(e1.y), x1, acc1);
            acc0 = fmaf(__uint_as_float(e2.y), x2, acc0);
            acc1 = fmaf(__uint_as_float(e3.y), x3, acc1);
            acc0 = fmaf(__uint_as_float(e4.y), x4, acc0);
            acc1 = fmaf(__uint_as_float(e5.y), x5, acc1);
            acc0 = fmaf(__uint_as_float(e6.y), x6, acc0);
            acc1 = fmaf(__uint_as_float(e7.y), x7, acc1);
        }
        for (; jj < jend; ++jj) {
            uint2 e = sorted[jj];
            acc0 = fmaf(__uint_as_float(e.y),
                        xt[(size_t)(e.x & SRC_MASK) * NB + b], acc0);
        }
        yt[(size_t)m * NB + b] = acc0 + acc1;
    }
}

// ---------------------------------------------------------------------------
// Fixup: apply overflow edges (statistically zero) with global atomics.
// Runs AFTER sort_gather (which writes yt with plain stores).
// ---------------------------------------------------------------------------
__global__ void fixup_kernel(const int* __restrict__ ovCount,
                             const int* __restrict__ ovList,
                             const int* __restrict__ src,
                             const int* __restrict__ dst,
                             const float* __restrict__ vals,
                             const float* __restrict__ xt,
                             float* __restrict__ yt) {
    long long total = (long long)(*ovCount) * 32;
    long long stride = (long long)gridDim.x * blockDim.x;
    for (long long i = (long long)blockIdx.x * blockDim.x + threadIdx.x;
         i < total; i += stride) {
        int k = (int)(i >> 5);
        int b = (int)(i & 31);
        int e = ovList[k];
        atomicAdd(&yt[(size_t)dst[e] * NB + b],
                  vals[e] * xt[(size_t)src[e] * NB + b]);
    }
}

// ---------------------------------------------------------------------------
// yt (M, B) -> out (B, M), + bias: 32x32 LDS tile transpose.
// ---------------------------------------------------------------------------
__global__ void finalize_kernel(const float* __restrict__ yt,
                                const float* __restrict__ bias,
                                float* __restrict__ out, int M) {
    __shared__ float tile[32][33];
    int m0 = blockIdx.x * 32;
    for (int i = threadIdx.y; i < 32; i += 8) {
        int m = m0 + i;
        tile[i][threadIdx.x] = (m < M) ? yt[(size_t)m * NB + threadIdx.x] : 0.f;
    }
    __syncthreads();
    for (int i = threadIdx.y; i < 32; i += 8) {
        int m = m0 + threadIdx.x;
        if (m < M) out[(size_t)i * M + m] = tile[threadIdx.x][i] + bias[m];
    }
}

// ---------------------------------------------------------------------------
// Fallback (verified round-0 path): global-atomic scatter. Used only if
// ws_size can't hold the CSR buffers.
// ---------------------------------------------------------------------------
__global__ void scatter_kernel(const int* __restrict__ src,
                               const int* __restrict__ dst,
                               const float* __restrict__ vals,
                               const float* __restrict__ xt,
                               float* __restrict__ yt, int nnz) {
    long long tid = (long long)blockIdx.x * blockDim.x + threadIdx.x;
    int e = (int)(tid >> 5);
    if (e >= nnz) return;
    int b = (int)(tid & 31);
    atomicAdd(&yt[(size_t)dst[e] * NB + b], vals[e] * xt[(size_t)src[e] * NB + b]);
}

extern "C" void kernel_launch(void* const* d_in, const int* in_sizes, int n_in,
                              void* d_out, int out_size, void* d_ws, size_t ws_size,
                              hipStream_t stream) {
    const float* x       = (const float*)d_in[0];   // (B, N, 1) fp32
    const int*   indices = (const int*)  d_in[1];   // (2, NNZ) int32
    const float* vals    = (const float*)d_in[2];   // (NNZ,) fp32
    const float* bias    = (const float*)d_in[3];   // (M, 1) fp32

    float* out = (float*)d_out;                     // (B, M, 1) fp32

    int nnz = in_sizes[1] / 2;
    int N   = in_sizes[0] / NB;
    int M   = in_sizes[3];

    const int* src = indices;        // row 0
    const int* dst = indices + nnz;  // row 1

    int nbins = (M + BIN_ROWS - 1) >> BIN_SHIFT;   // 1563 for M=100000

    // workspace layout (primary path, ~77 MB):
    //   xt        N*NB f32            (12.8 MB)
    //   yt        M*NB f32            (12.8 MB)
    //   binCursor NBINS_MAX i32
    //   ovCount   1 i32 (+pad)
    //   ovList    nnz i32             (12.8 MB)
    //   csr       nbins*CAP uint2     (38.4 MB)
    float* xt        = (float*)d_ws;
    float* yt        = xt + (size_t)N * NB;
    int*   binCursor = (int*)(yt + (size_t)M * NB);
    int*   ovCount   = binCursor + NBINS_MAX;
    int*   ovList    = ovCount + 4;
    uint2* csr       = (uint2*)(((uintptr_t)(ovList + nnz) + 15) &
                                ~(uintptr_t)15);

    size_t need = (size_t)((char*)(csr + (size_t)nbins * CAP) - (char*)d_ws);

    transpose_x_kernel<<<(N + 31) / 32, dim3(32, 8), 0, stream>>>(x, xt, N);

    if (ws_size >= need) {
        init_cursor<<<(nbins + 255) / 256, 256, 0, stream>>>(binCursor,
                                                             ovCount, nbins);
        int fgrid = (nnz + FCHUNK - 1) / FCHUNK;  // 391
        bin_fill<<<fgrid, FTHREADS, 0, stream>>>(src, dst, vals, binCursor,
                                                 csr, ovCount, ovList,
                                                 nnz, nbins);
        sort_gather<<<nbins, 256, 0, stream>>>(binCursor, csr, xt, yt, M);
        fixup_kernel<<<32, 256, 0, stream>>>(ovCount, ovList, src, dst, vals,
                                             xt, yt);
    } else {
        // fallback: round-0 verified atomic path (needs only xt + yt)
        hipMemsetAsync(yt, 0, (size_t)M * NB * sizeof(float), stream);
        long long pairs = (long long)nnz * NB;
        int grid = (int)((pairs + 255) / 256);
        scatter_kernel<<<grid, 256, 0, stream>>>(src, dst, vals, xt, yt, nnz);
    }

    finalize_kernel<<<(M + 31) / 32, dim3(32, 8), 0, stream>>>(yt, bias, out, M);
}

// Round 7
// 241.257 us; speedup vs baseline: 3.6566x; 1.0346x over previous
//
#include <hip/hip_runtime.h>
#include <stdint.h>

#define NB 32          // batch size B (fixed by problem)
#define BIN_SHIFT 6    // 64 dst rows per bin
#define BIN_ROWS 64
#define NBINS_MAX 2048 // supports M <= 131072
#define FCHUNK 16384   // edges per fill block (halves run overhead vs 8192)
#define FTHREADS 1024  // fill threads: 16 waves/block
#define EPT (FCHUNK / FTHREADS)  // edges per thread (16)
#define SRC_BITS 18    // N < 262144 (problem: N = 100000)
#define SRC_MASK ((1u << SRC_BITS) - 1)
#define CAP 3072       // fixed bin capacity: mean 2048 + 22 sigma

// ---------------------------------------------------------------------------
// x (B, N) -> xt (N, B): 32x32 LDS tile transpose, coalesced read and write.
// ---------------------------------------------------------------------------
__global__ void transpose_x_kernel(const float* __restrict__ x,
                                   float* __restrict__ xt, int N) {
    __shared__ float tile[32][33];  // +1 pad: avoid bank conflicts
    int n0 = blockIdx.x * 32;
    for (int i = threadIdx.y; i < 32; i += 8) {
        int n = n0 + threadIdx.x;
        tile[i][threadIdx.x] = (n < N) ? x[(size_t)i * N + n] : 0.f;
    }
    __syncthreads();
    for (int i = threadIdx.y; i < 32; i += 8) {
        int n = n0 + i;
        if (n < N) xt[(size_t)n * NB + threadIdx.x] = tile[threadIdx.x][i];
    }
}

// ---------------------------------------------------------------------------
// binCursor[i] = i*CAP (fixed-capacity bins — no global hist/scan needed).
// ---------------------------------------------------------------------------
__global__ void init_cursor(int* __restrict__ binCursor,
                            int* __restrict__ ovCount, int nbins) {
    int i = blockIdx.x * blockDim.x + threadIdx.x;
    if (i < nbins) binCursor[i] = i * CAP;
    if (i == 0) *ovCount = 0;
}

// ---------------------------------------------------------------------------
// Binned fill: per-block LDS hist -> one cursor claim per (block,bin) ->
// ranked write. Same-bin edges from one block are CONTIGUOUS in csr.
// Entry: meta = (dst&63) << 18 | src, val bits.
// dst values cached in registers across the two passes (no L2 re-read).
// Fixed-cap bins: slots beyond the bin's cap spill edge-ids to ovList
// (statistically never: cap = mean + 22 sigma), fixed up after gather.
// ---------------------------------------------------------------------------
__global__ void bin_fill(const int* __restrict__ src,
                         const int* __restrict__ dst,
                         const float* __restrict__ vals,
                         int* __restrict__ binCursor,
                         uint2* __restrict__ csr,
                         int* __restrict__ ovCount,
                         int* __restrict__ ovList,
                         int nnz, int nbins) {
    __shared__ int lhist[NBINS_MAX];
    __shared__ int lbase[NBINS_MAX];
    int t = threadIdx.x;
    int e0 = blockIdx.x * FCHUNK;
    int dcache[EPT];
    for (int i = t; i < nbins; i += FTHREADS) lhist[i] = 0;
    __syncthreads();
#pragma unroll 4
    for (int k = 0; k < EPT; ++k) {
        int e = e0 + k * FTHREADS + t;
        int d = (e < nnz) ? dst[e] : -1;
        dcache[k] = d;
        if (d >= 0) atomicAdd(&lhist[d >> BIN_SHIFT], 1);
    }
    __syncthreads();
    for (int i = t; i < nbins; i += FTHREADS) {
        int c = lhist[i];
        lbase[i] = c ? atomicAdd(&binCursor[i], c) : 0;
        lhist[i] = 0;  // reuse as intra-block rank cursor
    }
    __syncthreads();
#pragma unroll 4
    for (int k = 0; k < EPT; ++k) {
        int e = e0 + k * FTHREADS + t;
        int d = dcache[k];
        if (d >= 0) {
            int bin = d >> BIN_SHIFT;
            int r = atomicAdd(&lhist[bin], 1);
            int slot = lbase[bin] + r;
            if (slot < (bin + 1) * CAP) {
                uint32_t meta = ((uint32_t)(d & (BIN_ROWS - 1)) << SRC_BITS) |
                                (uint32_t)src[e];
                csr[slot] = make_uint2(meta, __float_as_uint(vals[e]));
            } else {
                int op = atomicAdd(ovCount, 1);
                ovList[op] = e;   // ovList sized nnz: can never overflow
            }
        }
    }
}

// ---------------------------------------------------------------------------
// Fused sort + gather + bias + output-transpose, one block per 64-row bin:
//  1. counting-sort the bin's edges INTO LDS (hist -> scan -> LDS scatter);
//     fill guarantees cnt <= CAP.
//  2. each half-wave (32 lanes = 32 batch cols) gathers its rows from the
//     LDS-sorted list: pure register accumulation, 8-deep load pipeline,
//     NO atomics in the hot loop.
//  3. writes DIRECTLY to out (B, M) + bias: lane b's stores for the bin's
//     64 consecutive m form a 256B run per lane -> L2 merges to full lines.
// Deletes finalize kernel + the 25.6 MB yt round-trip.
// ---------------------------------------------------------------------------
__global__ __launch_bounds__(256) void sort_gather(
        const int* __restrict__ binCursor,
        const uint2* __restrict__ csr,
        const float* __restrict__ xt,
        const float* __restrict__ bias,
        float* __restrict__ out, int M) {
    __shared__ uint2 sorted[CAP];      // 24 KB
    __shared__ int rowCnt[BIN_ROWS];
    __shared__ int rowOff[BIN_ROWS];
    int t = threadIdx.x;
    int bin = blockIdx.x;
    int start = bin * CAP;
    int cnt   = min(binCursor[bin] - start, CAP);
    int end   = start + cnt;
    int g = t >> 5;   // half-wave id 0..7
    int b = t & 31;   // batch lane

    if (t < BIN_ROWS) rowCnt[t] = 0;
    __syncthreads();
    for (int j = start + t; j < end; j += 256)
        atomicAdd(&rowCnt[csr[j].x >> SRC_BITS], 1);
    __syncthreads();
    if (t == 0) {
        int run = 0;
#pragma unroll
        for (int r = 0; r < BIN_ROWS; ++r) {
            rowOff[r] = run;
            run += rowCnt[r];
        }
    }
    __syncthreads();
    for (int j = start + t; j < end; j += 256) {
        uint2 e = csr[j];   // L2-hot (read in hist pass)
        int p = atomicAdd(&rowOff[e.x >> SRC_BITS], 1);
        sorted[p] = e;
    }
    __syncthreads();
    // after scatter, rowOff[r] == end of row r; start = end - rowCnt[r]
    for (int r = g; r < BIN_ROWS; r += 8) {
        int m = bin * BIN_ROWS + r;
        if (m >= M) break;
        int jend = rowOff[r];
        int jj   = jend - rowCnt[r];
        float acc0 = 0.f, acc1 = 0.f;
        for (; jj + 8 <= jend; jj += 8) {
            uint2 e0 = sorted[jj + 0];
            uint2 e1 = sorted[jj + 1];
            uint2 e2 = sorted[jj + 2];
            uint2 e3 = sorted[jj + 3];
            uint2 e4 = sorted[jj + 4];
            uint2 e5 = sorted[jj + 5];
            uint2 e6 = sorted[jj + 6];
            uint2 e7 = sorted[jj + 7];
            float x0 = xt[(size_t)(e0.x & SRC_MASK) * NB + b];
            float x1 = xt[(size_t)(e1.x & SRC_MASK) * NB + b];
            float x2 = xt[(size_t)(e2.x & SRC_MASK) * NB + b];
            float x3 = xt[(size_t)(e3.x & SRC_MASK) * NB + b];
            float x4 = xt[(size_t)(e4.x & SRC_MASK) * NB + b];
            float x5 = xt[(size_t)(e5.x & SRC_MASK) * NB + b];
            float x6 = xt[(size_t)(e6.x & SRC_MASK) * NB + b];
            float x7 = xt[(size_t)(e7.x & SRC_MASK) * NB + b];
            acc0 = fmaf(__uint_as_float(e0.y), x0, acc0);
            acc1 = fmaf(__uint_as_float(e1.y), x1, acc1);
            acc0 = fmaf(__uint_as_float(e2.y), x2, acc0);
            acc1 = fmaf(__uint_as_float(e3.y), x3, acc1);
            acc0 = fmaf(__uint_as_float(e4.y), x4, acc0);
            acc1 = fmaf(__uint_as_float(e5.y), x5, acc1);
            acc0 = fmaf(__uint_as_float(e6.y), x6, acc0);
            acc1 = fmaf(__uint_as_float(e7.y), x7, acc1);
        }
        for (; jj < jend; ++jj) {
            uint2 e = sorted[jj];
            acc0 = fmaf(__uint_as_float(e.y),
                        xt[(size_t)(e.x & SRC_MASK) * NB + b], acc0);
        }
        out[(size_t)b * M + m] = acc0 + acc1 + bias[m];
    }
}

// ---------------------------------------------------------------------------
// Fixup: apply overflow edges (statistically zero) with global atomics,
// directly into out (B, M). Runs AFTER sort_gather (plain stores done).
// ---------------------------------------------------------------------------
__global__ void fixup_kernel(const int* __restrict__ ovCount,
                             const int* __restrict__ ovList,
                             const int* __restrict__ src,
                             const int* __restrict__ dst,
                             const float* __restrict__ vals,
                             const float* __restrict__ xt,
                             float* __restrict__ out, int M) {
    long long total = (long long)(*ovCount) * 32;
    long long stride = (long long)gridDim.x * blockDim.x;
    for (long long i = (long long)blockIdx.x * blockDim.x + threadIdx.x;
         i < total; i += stride) {
        int k = (int)(i >> 5);
        int b = (int)(i & 31);
        int e = ovList[k];
        atomicAdd(&out[(size_t)b * M + dst[e]],
                  vals[e] * xt[(size_t)src[e] * NB + b]);
    }
}

// ---------------------------------------------------------------------------
// yt (M, B) -> out (B, M), + bias (fallback path only).
// ---------------------------------------------------------------------------
__global__ void finalize_kernel(const float* __restrict__ yt,
                                const float* __restrict__ bias,
                                float* __restrict__ out, int M) {
    __shared__ float tile[32][33];
    int m0 = blockIdx.x * 32;
    for (int i = threadIdx.y; i < 32; i += 8) {
        int m = m0 + i;
        tile[i][threadIdx.x] = (m < M) ? yt[(size_t)m * NB + threadIdx.x] : 0.f;
    }
    __syncthreads();
    for (int i = threadIdx.y; i < 32; i += 8) {
        int m = m0 + threadIdx.x;
        if (m < M) out[(size_t)i * M + m] = tile[threadIdx.x][i] + bias[m];
    }
}

// ---------------------------------------------------------------------------
// Fallback (verified round-0 path): global-atomic scatter. Used only if
// ws_size can't hold the CSR buffers.
// ---------------------------------------------------------------------------
__global__ void scatter_kernel(const int* __restrict__ src,
                               const int* __restrict__ dst,
                               const float* __restrict__ vals,
                               const float* __restrict__ xt,
                               float* __restrict__ yt, int nnz) {
    long long tid = (long long)blockIdx.x * blockDim.x + threadIdx.x;
    int e = (int)(tid >> 5);
    if (e >= nnz) return;
    int b = (int)(tid & 31);
    atomicAdd(&yt[(size_t)dst[e] * NB + b], vals[e] * xt[(size_t)src[e] * NB + b]);
}

extern "C" void kernel_launch(void* const* d_in, const int* in_sizes, int n_in,
                              void* d_out, int out_size, void* d_ws, size_t ws_size,
                              hipStream_t stream) {
    const float* x       = (const float*)d_in[0];   // (B, N, 1) fp32
    const int*   indices = (const int*)  d_in[1];   // (2, NNZ) int32
    const float* vals    = (const float*)d_in[2];   // (NNZ,) fp32
    const float* bias    = (const float*)d_in[3];   // (M, 1) fp32

    float* out = (float*)d_out;                     // (B, M, 1) fp32

    int nnz = in_sizes[1] / 2;
    int N   = in_sizes[0] / NB;
    int M   = in_sizes[3];

    const int* src = indices;        // row 0
    const int* dst = indices + nnz;  // row 1

    int nbins = (M + BIN_ROWS - 1) >> BIN_SHIFT;   // 1563 for M=100000

    // workspace layout (primary path, ~77 MB):
    //   xt        N*NB f32            (12.8 MB)
    //   yt        M*NB f32            (12.8 MB, fallback only)
    //   binCursor NBINS_MAX i32
    //   ovCount   1 i32 (+pad)
    //   ovList    nnz i32             (12.8 MB)
    //   csr       nbins*CAP uint2     (38.4 MB)
    float* xt        = (float*)d_ws;
    float* yt        = xt + (size_t)N * NB;
    int*   binCursor = (int*)(yt + (size_t)M * NB);
    int*   ovCount   = binCursor + NBINS_MAX;
    int*   ovList    = ovCount + 4;
    uint2* csr       = (uint2*)(((uintptr_t)(ovList + nnz) + 15) &
                                ~(uintptr_t)15);

    size_t need = (size_t)((char*)(csr + (size_t)nbins * CAP) - (char*)d_ws);

    transpose_x_kernel<<<(N + 31) / 32, dim3(32, 8), 0, stream>>>(x, xt, N);

    if (ws_size >= need) {
        init_cursor<<<(nbins + 255) / 256, 256, 0, stream>>>(binCursor,
                                                             ovCount, nbins);
        int fgrid = (nnz + FCHUNK - 1) / FCHUNK;  // 196
        bin_fill<<<fgrid, FTHREADS, 0, stream>>>(src, dst, vals, binCursor,
                                                 csr, ovCount, ovList,
                                                 nnz, nbins);
        sort_gather<<<nbins, 256, 0, stream>>>(binCursor, csr, xt, bias,
                                               out, M);
        fixup_kernel<<<32, 256, 0, stream>>>(ovCount, ovList, src, dst, vals,
                                             xt, out, M);
    } else {
        // fallback: round-0 verified atomic path (needs only xt + yt)
        hipMemsetAsync(yt, 0, (size_t)M * NB * sizeof(float), stream);
        long long pairs = (long long)nnz * NB;
        int grid = (int)((pairs + 255) / 256);
        scatter_kernel<<<grid, 256, 0, stream>>>(src, dst, vals, xt, yt, nnz);
        finalize_kernel<<<(M + 31) / 32, dim3(32, 8), 0, stream>>>(yt, bias,
                                                                   out, M);
    }
}

// Round 8
// 213.922 us; speedup vs baseline: 4.1239x; 1.1278x over previous
//
#include <hip/hip_runtime.h>
#include <hip/hip_fp16.h>
#include <stdint.h>

#define NB 32          // batch size B (fixed by problem)
#define BIN_SHIFT 6    // 64 dst rows per bin
#define BIN_ROWS 64
#define NBINS_MAX 2048 // supports M <= 131072
#define FCHUNK 8192    // edges per fill block (proven-best config, r6: 81us)
#define FTHREADS 1024  // fill threads: 16 waves/block
#define EPT (FCHUNK / FTHREADS)  // edges per thread (8)
#define SRC_BITS 18    // N < 262144 (problem: N = 100000)
#define SRC_MASK ((1u << SRC_BITS) - 1)
#define CAP 2816       // fixed bin capacity: mean 2048 + 17 sigma
#define MAXK 11        // CAP / 256 entries per thread in sort_gather

// ---------------------------------------------------------------------------
// x (B, N) f32 -> xt (N, B) f16: 32x32 LDS tile transpose.
// fp16 storage halves the gather footprint (12.8 -> 6.4 MB): the gather
// fetch is ~ 8 XCDs x footprint, so this halves sort_gather's FETCH.
// Accumulation stays fp32.
// ---------------------------------------------------------------------------
__global__ void transpose_x_kernel(const float* __restrict__ x,
                                   __half* __restrict__ xt, int N) {
    __shared__ float tile[32][33];  // +1 pad: avoid bank conflicts
    int n0 = blockIdx.x * 32;
    for (int i = threadIdx.y; i < 32; i += 8) {
        int n = n0 + threadIdx.x;
        tile[i][threadIdx.x] = (n < N) ? x[(size_t)i * N + n] : 0.f;
    }
    __syncthreads();
    for (int i = threadIdx.y; i < 32; i += 8) {
        int n = n0 + i;
        if (n < N) xt[(size_t)n * NB + threadIdx.x] =
            __float2half(tile[threadIdx.x][i]);
    }
}

// ---------------------------------------------------------------------------
// Binned fill: per-block LDS hist -> one RELATIVE cursor claim per
// (block,bin) -> ranked write. Same-bin edges from one block are CONTIGUOUS
// in csr. Entry: meta = (dst&63) << 18 | src, val bits.
// Cursors are bin-relative (init by plain memset-0); slot = bin*CAP + rel.
// Overflow (rel >= CAP, statistically never at mean+17sigma) spills edge-ids
// to ovList, applied by fixup after the gather.
// ---------------------------------------------------------------------------
__global__ void bin_fill(const int* __restrict__ src,
                         const int* __restrict__ dst,
                         const float* __restrict__ vals,
                         int* __restrict__ binCursor,
                         uint2* __restrict__ csr,
                         int* __restrict__ ovCount,
                         int* __restrict__ ovList,
                         int nnz, int nbins) {
    __shared__ int lhist[NBINS_MAX];
    __shared__ int lbase[NBINS_MAX];
    int t = threadIdx.x;
    int e0 = blockIdx.x * FCHUNK;
    int dcache[EPT];
    for (int i = t; i < nbins; i += FTHREADS) lhist[i] = 0;
    __syncthreads();
#pragma unroll
    for (int k = 0; k < EPT; ++k) {
        int e = e0 + k * FTHREADS + t;
        int d = (e < nnz) ? dst[e] : -1;
        dcache[k] = d;
        if (d >= 0) atomicAdd(&lhist[d >> BIN_SHIFT], 1);
    }
    __syncthreads();
    for (int i = t; i < nbins; i += FTHREADS) {
        int c = lhist[i];
        lbase[i] = c ? atomicAdd(&binCursor[i], c) : 0;  // relative offset
        lhist[i] = 0;  // reuse as intra-block rank cursor
    }
    __syncthreads();
#pragma unroll
    for (int k = 0; k < EPT; ++k) {
        int e = e0 + k * FTHREADS + t;
        int d = dcache[k];
        if (d >= 0) {
            int bin = d >> BIN_SHIFT;
            int r = lbase[bin] + atomicAdd(&lhist[bin], 1);  // relative slot
            if (r < CAP) {
                uint32_t meta = ((uint32_t)(d & (BIN_ROWS - 1)) << SRC_BITS) |
                                (uint32_t)src[e];
                csr[(size_t)bin * CAP + r] =
                    make_uint2(meta, __float_as_uint(vals[e]));
            } else {
                int op = atomicAdd(ovCount, 1);
                ovList[op] = e;   // ovList sized nnz: can never overflow
            }
        }
    }
}

// ---------------------------------------------------------------------------
// Fused sort + gather + bias + output-transpose, one block per 64-row bin:
//  1. read the bin's csr entries ONCE into registers (compile-time indexed,
//     <= MAXK per thread); LDS-hist -> scan -> LDS scatter from registers.
//  2. each half-wave (32 lanes = 32 batch cols) gathers its rows from the
//     LDS-sorted list: fp16 xt loads, fp32 register accumulation, 8-deep
//     load pipeline, NO atomics in the hot loop.
//  3. writes DIRECTLY to out (B, M) + bias: lane b's stores for the bin's
//     64 consecutive m form a 256B run per lane -> L2 merges to lines.
// ---------------------------------------------------------------------------
__global__ __launch_bounds__(256) void sort_gather(
        const int* __restrict__ binCursor,
        const uint2* __restrict__ csr,
        const __half* __restrict__ xt,
        const float* __restrict__ bias,
        float* __restrict__ out, int M) {
    __shared__ uint2 sorted[CAP];      // 22 KB
    __shared__ int rowCnt[BIN_ROWS];
    __shared__ int rowOff[BIN_ROWS];
    int t = threadIdx.x;
    int bin = blockIdx.x;
    int start = bin * CAP;
    int cnt   = min(binCursor[bin], CAP);
    int g = t >> 5;   // half-wave id 0..7
    int b = t & 31;   // batch lane

    // single global read of the bin's edges into registers
    uint2 reg[MAXK];
#pragma unroll
    for (int k = 0; k < MAXK; ++k) {
        int j = t + k * 256;
        if (j < cnt) reg[k] = csr[start + j];
    }
    if (t < BIN_ROWS) rowCnt[t] = 0;
    __syncthreads();
#pragma unroll
    for (int k = 0; k < MAXK; ++k) {
        int j = t + k * 256;
        if (j < cnt) atomicAdd(&rowCnt[reg[k].x >> SRC_BITS], 1);
    }
    __syncthreads();
    if (t == 0) {
        int run = 0;
#pragma unroll
        for (int r = 0; r < BIN_ROWS; ++r) {
            rowOff[r] = run;
            run += rowCnt[r];
        }
    }
    __syncthreads();
#pragma unroll
    for (int k = 0; k < MAXK; ++k) {
        int j = t + k * 256;
        if (j < cnt) {
            int p = atomicAdd(&rowOff[reg[k].x >> SRC_BITS], 1);
            sorted[p] = reg[k];
        }
    }
    __syncthreads();
    // after scatter, rowOff[r] == end of row r; start = end - rowCnt[r]
    for (int r = g; r < BIN_ROWS; r += 8) {
        int m = bin * BIN_ROWS + r;
        if (m >= M) break;
        int jend = rowOff[r];
        int jj   = jend - rowCnt[r];
        float acc0 = 0.f, acc1 = 0.f;
        for (; jj + 8 <= jend; jj += 8) {
            uint2 e0 = sorted[jj + 0];
            uint2 e1 = sorted[jj + 1];
            uint2 e2 = sorted[jj + 2];
            uint2 e3 = sorted[jj + 3];
            uint2 e4 = sorted[jj + 4];
            uint2 e5 = sorted[jj + 5];
            uint2 e6 = sorted[jj + 6];
            uint2 e7 = sorted[jj + 7];
            float x0 = __half2float(xt[(size_t)(e0.x & SRC_MASK) * NB + b]);
            float x1 = __half2float(xt[(size_t)(e1.x & SRC_MASK) * NB + b]);
            float x2 = __half2float(xt[(size_t)(e2.x & SRC_MASK) * NB + b]);
            float x3 = __half2float(xt[(size_t)(e3.x & SRC_MASK) * NB + b]);
            float x4 = __half2float(xt[(size_t)(e4.x & SRC_MASK) * NB + b]);
            float x5 = __half2float(xt[(size_t)(e5.x & SRC_MASK) * NB + b]);
            float x6 = __half2float(xt[(size_t)(e6.x & SRC_MASK) * NB + b]);
            float x7 = __half2float(xt[(size_t)(e7.x & SRC_MASK) * NB + b]);
            acc0 = fmaf(__uint_as_float(e0.y), x0, acc0);
            acc1 = fmaf(__uint_as_float(e1.y), x1, acc1);
            acc0 = fmaf(__uint_as_float(e2.y), x2, acc0);
            acc1 = fmaf(__uint_as_float(e3.y), x3, acc1);
            acc0 = fmaf(__uint_as_float(e4.y), x4, acc0);
            acc1 = fmaf(__uint_as_float(e5.y), x5, acc1);
            acc0 = fmaf(__uint_as_float(e6.y), x6, acc0);
            acc1 = fmaf(__uint_as_float(e7.y), x7, acc1);
        }
        for (; jj < jend; ++jj) {
            uint2 e = sorted[jj];
            acc0 = fmaf(__uint_as_float(e.y),
                        __half2float(xt[(size_t)(e.x & SRC_MASK) * NB + b]),
                        acc0);
        }
        out[(size_t)b * M + m] = acc0 + acc1 + bias[m];
    }
}

// ---------------------------------------------------------------------------
// Fixup: apply overflow edges (statistically zero) with global atomics,
// directly into out (B, M). Runs AFTER sort_gather (plain stores done).
// ---------------------------------------------------------------------------
__global__ void fixup_kernel(const int* __restrict__ ovCount,
                             const int* __restrict__ ovList,
                             const int* __restrict__ src,
                             const int* __restrict__ dst,
                             const float* __restrict__ vals,
                             const __half* __restrict__ xt,
                             float* __restrict__ out, int M) {
    long long total = (long long)(*ovCount) * 32;
    long long stride = (long long)gridDim.x * blockDim.x;
    for (long long i = (long long)blockIdx.x * blockDim.x + threadIdx.x;
         i < total; i += stride) {
        int k = (int)(i >> 5);
        int b = (int)(i & 31);
        int e = ovList[k];
        atomicAdd(&out[(size_t)b * M + dst[e]],
                  vals[e] * __half2float(xt[(size_t)src[e] * NB + b]));
    }
}

// ---------------------------------------------------------------------------
// yt (M, B) -> out (B, M), + bias (fallback path only).
// ---------------------------------------------------------------------------
__global__ void finalize_kernel(const float* __restrict__ yt,
                                const float* __restrict__ bias,
                                float* __restrict__ out, int M) {
    __shared__ float tile[32][33];
    int m0 = blockIdx.x * 32;
    for (int i = threadIdx.y; i < 32; i += 8) {
        int m = m0 + i;
        tile[i][threadIdx.x] = (m < M) ? yt[(size_t)m * NB + threadIdx.x] : 0.f;
    }
    __syncthreads();
    for (int i = threadIdx.y; i < 32; i += 8) {
        int m = m0 + threadIdx.x;
        if (m < M) out[(size_t)i * M + m] = tile[threadIdx.x][i] + bias[m];
    }
}

// ---------------------------------------------------------------------------
// Fallback (round-0 structure): global-atomic scatter. Used only if ws_size
// can't hold the CSR buffers.
// ---------------------------------------------------------------------------
__global__ void scatter_kernel(const int* __restrict__ src,
                               const int* __restrict__ dst,
                               const float* __restrict__ vals,
                               const __half* __restrict__ xt,
                               float* __restrict__ yt, int nnz) {
    long long tid = (long long)blockIdx.x * blockDim.x + threadIdx.x;
    int e = (int)(tid >> 5);
    if (e >= nnz) return;
    int b = (int)(tid & 31);
    atomicAdd(&yt[(size_t)dst[e] * NB + b],
              vals[e] * __half2float(xt[(size_t)src[e] * NB + b]));
}

extern "C" void kernel_launch(void* const* d_in, const int* in_sizes, int n_in,
                              void* d_out, int out_size, void* d_ws, size_t ws_size,
                              hipStream_t stream) {
    const float* x       = (const float*)d_in[0];   // (B, N, 1) fp32
    const int*   indices = (const int*)  d_in[1];   // (2, NNZ) int32
    const float* vals    = (const float*)d_in[2];   // (NNZ,) fp32
    const float* bias    = (const float*)d_in[3];   // (M, 1) fp32

    float* out = (float*)d_out;                     // (B, M, 1) fp32

    int nnz = in_sizes[1] / 2;
    int N   = in_sizes[0] / NB;
    int M   = in_sizes[3];

    const int* src = indices;        // row 0
    const int* dst = indices + nnz;  // row 1

    int nbins = (M + BIN_ROWS - 1) >> BIN_SHIFT;   // 1563 for M=100000

    // workspace layout (primary path, ~67 MB):
    //   xt        N*NB f16            (6.4 MB)
    //   yt        M*NB f32            (12.8 MB, fallback only)
    //   binCursor NBINS_MAX i32 (relative, memset-0)
    //   ovCount   1 i32 (+pad)
    //   ovList    nnz i32             (12.8 MB)
    //   csr       nbins*CAP uint2     (35.2 MB)
    __half* xt       = (__half*)d_ws;
    float* yt        = (float*)(xt + (size_t)N * NB);
    int*   binCursor = (int*)(yt + (size_t)M * NB);
    int*   ovCount   = binCursor + NBINS_MAX;
    int*   ovList    = ovCount + 4;
    uint2* csr       = (uint2*)(((uintptr_t)(ovList + nnz) + 15) &
                                ~(uintptr_t)15);

    size_t need = (size_t)((char*)(csr + (size_t)nbins * CAP) - (char*)d_ws);

    transpose_x_kernel<<<(N + 31) / 32, dim3(32, 8), 0, stream>>>(x, xt, N);

    if (ws_size >= need) {
        // zero relative cursors + ovCount in one memset (adjacent)
        hipMemsetAsync(binCursor, 0, (NBINS_MAX + 4) * sizeof(int), stream);
        int fgrid = (nnz + FCHUNK - 1) / FCHUNK;  // 391
        bin_fill<<<fgrid, FTHREADS, 0, stream>>>(src, dst, vals, binCursor,
                                                 csr, ovCount, ovList,
                                                 nnz, nbins);
        sort_gather<<<nbins, 256, 0, stream>>>(binCursor, csr, xt, bias,
                                               out, M);
        fixup_kernel<<<32, 256, 0, stream>>>(ovCount, ovList, src, dst, vals,
                                             xt, out, M);
    } else {
        // fallback: atomic scatter (needs only xt + yt)
        hipMemsetAsync(yt, 0, (size_t)M * NB * sizeof(float), stream);
        long long pairs = (long long)nnz * NB;
        int grid = (int)((pairs + 255) / 256);
        scatter_kernel<<<grid, 256, 0, stream>>>(src, dst, vals, xt, yt, nnz);
        finalize_kernel<<<(M + 31) / 32, dim3(32, 8), 0, stream>>>(yt, bias,
                                                                   out, M);
    }
}